// Round 1
// baseline (1583.249 us; speedup 1.0000x reference)
//
#include <hip/hip_runtime.h>

// Problem constants
// x: (2,64,32,32,32) f32; N = 2*32*32 = 2048 rows of (C=64, L=32)
// qkv: (N,128,32); sim: (N,24,32,32); out: (2,64,32,32,32)
#define NROWS 2048
#define NC 64
#define LL 32
#define O2 128

__device__ __forceinline__ float half_reduce_sum(float v) {
    #pragma unroll
    for (int m = 16; m >= 1; m >>= 1) v += __shfl_xor(v, m);
    return v;
}
__device__ __forceinline__ float wave_reduce_sum(float v) {
    #pragma unroll
    for (int m = 32; m >= 1; m >>= 1) v += __shfl_xor(v, m);
    return v;
}
__device__ __forceinline__ float half_reduce_max(float v) {
    #pragma unroll
    for (int m = 16; m >= 1; m >>= 1) v = fmaxf(v, __shfl_xor(v, m));
    return v;
}

// K1: qkv[n,o,l] = sum_c w[o,c] * x[b,c,h,w,l]; accumulate per-o sum/sumsq
__global__ __launch_bounds__(256) void k_qkv(const float* __restrict__ x,
                                             const float* __restrict__ w,
                                             float* __restrict__ qkv,
                                             float* __restrict__ sqkv) {
    int n = blockIdx.x;
    int t = threadIdx.x;
    int b = n >> 10, hw = n & 1023;
    __shared__ float xs[64][32];
    __shared__ float wls[128 * 64];
    const float* xb = x + (size_t)b * 2097152 + (size_t)(hw >> 5) * 1024 + (size_t)(hw & 31) * 32;
    #pragma unroll
    for (int r = 0; r < 8; ++r) {
        int idx = t + 256 * r;
        int c = idx >> 5, l = idx & 31;
        xs[c][l] = xb[(size_t)c * 32768 + l];
    }
    #pragma unroll
    for (int r = 0; r < 32; ++r) wls[t + 256 * r] = w[t + 256 * r];
    __syncthreads();

    int l = t & 31, ob = t >> 5;  // ob in 0..7
    float acc[16];
    #pragma unroll
    for (int ot = 0; ot < 16; ++ot) acc[ot] = 0.f;
    for (int c = 0; c < 64; ++c) {
        float xv = xs[c][l];
        #pragma unroll
        for (int ot = 0; ot < 16; ++ot) acc[ot] += wls[(ob + 8 * ot) * 64 + c] * xv;
    }
    float* qn = qkv + (size_t)n * 4096;
    #pragma unroll
    for (int ot = 0; ot < 16; ++ot) {
        int o = ob + 8 * ot;
        qn[o * 32 + l] = acc[ot];
        float s1 = half_reduce_sum(acc[ot]);
        float s2 = half_reduce_sum(acc[ot] * acc[ot]);
        if (l == 0) {
            atomicAdd(&sqkv[o], s1);
            atomicAdd(&sqkv[128 + o], s2);
        }
    }
}

// K2: finalize qkv BN affine; build emb table emb[c][i][j] = rel[c, i-j+31]
__global__ __launch_bounds__(1024) void k_fin_qkv(const float* __restrict__ sqkv,
                                                  const float* __restrict__ g,
                                                  const float* __restrict__ b,
                                                  float* __restrict__ aqkv,
                                                  const float* __restrict__ rel,
                                                  float* __restrict__ emb) {
    int t = threadIdx.x;
    if (t < 128) {
        float m = sqkv[t] * (1.0f / 65536.0f);
        float v = sqkv[128 + t] * (1.0f / 65536.0f) - m * m;
        float a = g[t] * rsqrtf(v + 1e-5f);
        aqkv[t] = a;
        aqkv[128 + t] = b[t] - m * a;
    }
    #pragma unroll
    for (int r = 0; r < 16; ++r) {
        int e = t + 1024 * r;
        int c = e >> 10, rr = e & 1023;
        int i = rr >> 5, j = rr & 31;
        emb[e] = rel[c * 63 + (i - j + 31)];
    }
}

// K3: recompute qe/ke/qk per (n,g); accumulate sim-BN sum/sumsq (24 channels)
__global__ __launch_bounds__(64) void k_sim_stats(const float* __restrict__ qkv,
                                                  const float* __restrict__ emb,
                                                  const float* __restrict__ aqkv,
                                                  float* __restrict__ ssim) {
    int blk = blockIdx.x;
    int n = blk >> 3, g = blk & 7;
    int t = threadIdx.x;
    int j = t & 31, h = t >> 5;
    __shared__ float qs[8][32];      // rows 0..3 = q_hat, 4..7 = k_hat
    __shared__ float qeS[32 * 32];
    __shared__ float keS[32 * 32];
    const float* qn = qkv + (size_t)n * 4096 + g * 16 * 32;
    #pragma unroll
    for (int r = 0; r < 4; ++r) {
        int idx = t + 64 * r;
        int cc = idx >> 5, i = idx & 31;
        float a = aqkv[g * 16 + cc], c = aqkv[128 + g * 16 + cc];
        qs[cc][i] = a * qn[cc * 32 + i] + c;
    }
    __syncthreads();
    float s_qe = 0, q2_qe = 0, s_ke = 0, q2_ke = 0;
    #pragma unroll
    for (int ii = 0; ii < 16; ++ii) {
        int i = h + 2 * ii;
        const float* er = emb + i * 32 + j;
        float qe = 0, ke = 0;
        #pragma unroll
        for (int c = 0; c < 4; ++c) {
            qe += qs[c][i] * er[c * 1024];
            ke += qs[4 + c][i] * er[(4 + c) * 1024];
        }
        qeS[i * 32 + j] = qe;
        keS[i * 32 + j] = ke;
        s_qe += qe; q2_qe += qe * qe;
        s_ke += ke; q2_ke += ke * ke;
    }
    __syncthreads();
    float s_qk = 0, q2_qk = 0;
    #pragma unroll 4
    for (int ii = 0; ii < 16; ++ii) {
        int i = h + 2 * ii;
        float qk = 0;
        for (int p = 0; p < 32; ++p) qk += qeS[p * 32 + i] * keS[p * 32 + j];
        s_qk += qk; q2_qk += qk * qk;
    }
    s_qk = wave_reduce_sum(s_qk);  q2_qk = wave_reduce_sum(q2_qk);
    s_qe = wave_reduce_sum(s_qe);  q2_qe = wave_reduce_sum(q2_qe);
    s_ke = wave_reduce_sum(s_ke);  q2_ke = wave_reduce_sum(q2_ke);
    if (t == 0) {
        atomicAdd(&ssim[g], s_qk);       atomicAdd(&ssim[24 + g], q2_qk);
        atomicAdd(&ssim[8 + g], s_qe);   atomicAdd(&ssim[24 + 8 + g], q2_qe);
        atomicAdd(&ssim[16 + g], s_ke);  atomicAdd(&ssim[24 + 16 + g], q2_ke);
    }
}

// K4: finalize sim BN affine (24 channels, count = N*32*32)
__global__ __launch_bounds__(64) void k_fin_sim(const float* __restrict__ ssim,
                                                const float* __restrict__ g,
                                                const float* __restrict__ b,
                                                float* __restrict__ asim) {
    int t = threadIdx.x;
    if (t >= 24) return;
    float m = ssim[t] * (1.0f / 2097152.0f);
    float v = ssim[24 + t] * (1.0f / 2097152.0f) - m * m;
    float a = g[t] * rsqrtf(v + 1e-5f);
    asim[t] = a;
    asim[24 + t] = b[t] - m * a;
}

// K5: full attention per (n,g): recompute qe/ke/qk, BN affine+sum, softmax,
//     am = P*v_hat, ame = P*ve_emb; write out_raw + out-BN stats
__global__ __launch_bounds__(64) void k_attn(const float* __restrict__ qkv,
                                             const float* __restrict__ emb,
                                             const float* __restrict__ aqkv,
                                             const float* __restrict__ asim,
                                             float* __restrict__ oraw,
                                             float* __restrict__ sout) {
    int blk = blockIdx.x;
    int n = blk >> 3, g = blk & 7;
    int t = threadIdx.x;
    int j = t & 31, h = t >> 5;
    __shared__ float qs[8][32];
    __shared__ float vs[8][32];
    __shared__ float qeS[32 * 32];
    __shared__ float keS[32 * 32];
    __shared__ float pS[32 * 33];  // padded: PV reads column-slices
    const float* qn = qkv + (size_t)n * 4096 + g * 16 * 32;
    #pragma unroll
    for (int r = 0; r < 4; ++r) {
        int idx = t + 64 * r;
        int cc = idx >> 5, i = idx & 31;
        float a = aqkv[g * 16 + cc], c = aqkv[128 + g * 16 + cc];
        qs[cc][i] = a * qn[cc * 32 + i] + c;
        int cv = 8 + cc;
        float av = aqkv[g * 16 + cv], bv = aqkv[128 + g * 16 + cv];
        vs[cc][i] = av * qn[cv * 32 + i] + bv;
    }
    __syncthreads();
    #pragma unroll
    for (int ii = 0; ii < 16; ++ii) {
        int i = h + 2 * ii;
        const float* er = emb + i * 32 + j;
        float qe = 0, ke = 0;
        #pragma unroll
        for (int c = 0; c < 4; ++c) {
            qe += qs[c][i] * er[c * 1024];
            ke += qs[4 + c][i] * er[(4 + c) * 1024];
        }
        qeS[i * 32 + j] = qe;
        keS[i * 32 + j] = ke;
    }
    __syncthreads();
    float aQK = asim[g], aQE = asim[8 + g], aKE = asim[16 + g];
    float csum = asim[24 + g] + asim[32 + g] + asim[40 + g];
    #pragma unroll 4
    for (int ii = 0; ii < 16; ++ii) {
        int i = h + 2 * ii;
        float qk = 0;
        for (int p = 0; p < 32; ++p) qk += qeS[p * 32 + i] * keS[p * 32 + j];
        float s = aQK * qk + aQE * qeS[i * 32 + j] + aKE * keS[i * 32 + j] + csum;
        float mx = half_reduce_max(s);
        float e = __expf(s - mx);
        float den = half_reduce_sum(e);
        pS[i * 33 + j] = e / den;
    }
    __syncthreads();
    float am[4], ame[4];
    #pragma unroll
    for (int k = 0; k < 4; ++k) {
        int idx = t + 64 * k;
        int c = idx >> 5, i = idx & 31;
        float acc = 0, acce = 0;
        const float* ver = emb + (8 + c) * 1024 + i * 32;
        for (int jj = 0; jj < 32; ++jj) {
            float p = pS[i * 33 + jj];
            acc += p * vs[c][jj];
            acce += p * ver[jj];
        }
        am[k] = acc;
        ame[k] = acce;
        oraw[(size_t)n * 4096 + (g * 16 + 2 * c) * 32 + i] = acc;
        oraw[(size_t)n * 4096 + (g * 16 + 2 * c + 1) * 32 + i] = acce;
    }
    #pragma unroll
    for (int k = 0; k < 4; ++k) {
        int idx = t + 64 * k;
        int c = idx >> 5, i = idx & 31;
        float s1 = half_reduce_sum(am[k]);
        float s2 = half_reduce_sum(am[k] * am[k]);
        if (i == 0) {
            int o = g * 16 + 2 * c;
            atomicAdd(&sout[o], s1);
            atomicAdd(&sout[128 + o], s2);
        }
        s1 = half_reduce_sum(ame[k]);
        s2 = half_reduce_sum(ame[k] * ame[k]);
        if (i == 0) {
            int o = g * 16 + 2 * c + 1;
            atomicAdd(&sout[o], s1);
            atomicAdd(&sout[128 + o], s2);
        }
    }
}

// K6: finalize out BN affine (128 channels, count = N*32)
__global__ __launch_bounds__(128) void k_fin_out(const float* __restrict__ sout,
                                                 const float* __restrict__ g,
                                                 const float* __restrict__ b,
                                                 float* __restrict__ aout) {
    int t = threadIdx.x;
    float m = sout[t] * (1.0f / 65536.0f);
    float v = sout[128 + t] * (1.0f / 65536.0f) - m * m;
    float a = g[t] * rsqrtf(v + 1e-5f);
    aout[t] = a;
    aout[128 + t] = b[t] - m * a;
}

// K7: out[b,oc,h,w,l] = bn(oraw[n,2oc,l]) + bn(oraw[n,2oc+1,l])
__global__ __launch_bounds__(256) void k_out(const float* __restrict__ oraw,
                                             const float* __restrict__ aout,
                                             float* __restrict__ out) {
    int gid = blockIdx.x * 256 + threadIdx.x;  // 1M float4s
    int l4 = gid & 7;
    int rest = gid >> 3;
    int w = rest & 31; rest >>= 5;
    int hh = rest & 31; rest >>= 5;
    int oc = rest & 63;
    int b = rest >> 6;
    int n = b * 1024 + hh * 32 + w;
    const float4 r0 = *(const float4*)(oraw + (size_t)n * 4096 + oc * 64 + l4 * 4);
    const float4 r1 = *(const float4*)(oraw + (size_t)n * 4096 + oc * 64 + 32 + l4 * 4);
    float a0 = aout[2 * oc], a1 = aout[2 * oc + 1];
    float cc = aout[128 + 2 * oc] + aout[128 + 2 * oc + 1];
    float4 o;
    o.x = a0 * r0.x + a1 * r1.x + cc;
    o.y = a0 * r0.y + a1 * r1.y + cc;
    o.z = a0 * r0.z + a1 * r1.z + cc;
    o.w = a0 * r0.w + a1 * r1.w + cc;
    *((float4*)out + gid) = o;
}

extern "C" void kernel_launch(void* const* d_in, const int* in_sizes, int n_in,
                              void* d_out, int out_size, void* d_ws, size_t ws_size,
                              hipStream_t stream) {
    const float* x   = (const float*)d_in[0];
    const float* w   = (const float*)d_in[1];
    const float* bqg = (const float*)d_in[2];
    const float* bqb = (const float*)d_in[3];
    const float* bsg = (const float*)d_in[4];
    const float* bsb = (const float*)d_in[5];
    const float* bog = (const float*)d_in[6];
    const float* bob = (const float*)d_in[7];
    const float* rel = (const float*)d_in[8];

    float* ws    = (float*)d_ws;
    float* qkv   = ws;                   // 8388608
    float* oraw  = ws + 8388608;         // 8388608
    float* emb   = ws + 16777216;        // 16384
    float* stats = ws + 16793600;        // sqkv 256 | ssim 64 | sout 256
    float* sqkv  = stats;
    float* ssim  = stats + 256;
    float* sout  = stats + 320;
    float* aqkv  = ws + 16794176;        // 256
    float* asim  = ws + 16794432;        // 64
    float* aout  = ws + 16794496;        // 256

    hipMemsetAsync(stats, 0, 576 * sizeof(float), stream);

    k_qkv<<<NROWS, 256, 0, stream>>>(x, w, qkv, sqkv);
    k_fin_qkv<<<1, 1024, 0, stream>>>(sqkv, bqg, bqb, aqkv, rel, emb);
    k_sim_stats<<<NROWS * 8, 64, 0, stream>>>(qkv, emb, aqkv, ssim);
    k_fin_sim<<<1, 64, 0, stream>>>(ssim, bsg, bsb, asim);
    k_attn<<<NROWS * 8, 64, 0, stream>>>(qkv, emb, aqkv, asim, oraw, sout);
    k_fin_out<<<1, 128, 0, stream>>>(sout, bog, bob, aout);
    k_out<<<4096, 256, 0, stream>>>(oraw, aout, (float*)d_out);
}

// Round 2
// 250.459 us; speedup vs baseline: 6.3214x; 6.3214x over previous
//
#include <hip/hip_runtime.h>

// x: (2,64,32,32,32) f32; N = 2048 rows of (C=64, L=32)
// qkv: (N,128,32); out: (2,64,32,32,32)
// Pair = (n, g), 16384 pairs. One wave (64 lanes) per pair, 4 pairs/block.

__device__ __forceinline__ float wave_reduce_sum(float v) {
    #pragma unroll
    for (int m = 32; m >= 1; m >>= 1) v += __shfl_xor(v, m);
    return v;
}
__device__ __forceinline__ float half_reduce_sum(float v) {
    #pragma unroll
    for (int m = 16; m >= 1; m >>= 1) v += __shfl_xor(v, m);
    return v;
}
__device__ __forceinline__ float oct_reduce_sum(float v) {
    v += __shfl_xor(v, 1); v += __shfl_xor(v, 2); v += __shfl_xor(v, 4);
    return v;
}
__device__ __forceinline__ float oct_reduce_max(float v) {
    v = fmaxf(v, __shfl_xor(v, 1)); v = fmaxf(v, __shfl_xor(v, 2)); v = fmaxf(v, __shfl_xor(v, 4));
    return v;
}

// ---------------- K1: qkv = w @ x, + per-channel sum/sumsq ----------------
// grid 4096 (2 blocks per n: o-halves), block 128. Register tile 4o x 4l.
__global__ __launch_bounds__(128) void k_qkv(const float* __restrict__ x,
                                             const float* __restrict__ w,
                                             float* __restrict__ qkv,
                                             float* __restrict__ sqkv) {
    __shared__ __attribute__((aligned(16))) float xs[64 * 32];
    __shared__ float ws65[64 * 65];   // padded rows: column reads conflict-free
    __shared__ float statQ[128];
    int bid = blockIdx.x;
    int n = bid >> 1, oh = bid & 1;
    int t = threadIdx.x;
    int b = n >> 10, hw = n & 1023;
    const float* xb = x + (size_t)b * 2097152 + (hw >> 5) * 1024 + (hw & 31) * 32;
    #pragma unroll
    for (int k = 0; k < 16; ++k) {
        int idx = t + 128 * k;
        int c = idx >> 5, l = idx & 31;
        xs[idx] = xb[c * 32768 + l];
    }
    const float* wbase = w + oh * 64 * 64;
    #pragma unroll
    for (int k = 0; k < 32; ++k) {
        int idx = t + 128 * k;
        int ol = idx >> 6, c = idx & 63;
        ws65[ol * 65 + c] = wbase[idx];
    }
    __syncthreads();
    int ti = t >> 3, tj = t & 7;  // ti 0..15 (o-tile), tj 0..7 (l-tile)
    float acc[4][4] = {};
    #pragma unroll 4
    for (int c = 0; c < 64; ++c) {
        float4 xv = *(const float4*)&xs[c * 32 + 4 * tj];
        float xa[4] = {xv.x, xv.y, xv.z, xv.w};
        #pragma unroll
        for (int oo = 0; oo < 4; ++oo) {
            float wv = ws65[(4 * ti + oo) * 65 + c];
            #pragma unroll
            for (int e = 0; e < 4; ++e) acc[oo][e] += wv * xa[e];
        }
    }
    float* qn = qkv + (size_t)n * 4096 + (oh * 64) * 32;
    #pragma unroll
    for (int oo = 0; oo < 4; ++oo) {
        int o = 4 * ti + oo;
        *(float4*)(qn + o * 32 + 4 * tj) =
            make_float4(acc[oo][0], acc[oo][1], acc[oo][2], acc[oo][3]);
        float s1 = acc[oo][0] + acc[oo][1] + acc[oo][2] + acc[oo][3];
        float s2 = acc[oo][0]*acc[oo][0] + acc[oo][1]*acc[oo][1]
                 + acc[oo][2]*acc[oo][2] + acc[oo][3]*acc[oo][3];
        s1 = oct_reduce_sum(s1);
        s2 = oct_reduce_sum(s2);
        if (tj == 0) { statQ[o * 2] = s1; statQ[o * 2 + 1] = s2; }
    }
    __syncthreads();
    if (t < 128) {
        int ch = oh * 64 + (t >> 1);
        atomicAdd(&sqkv[((t & 1) ? 128 : 0) + ch], statQ[t]);
    }
}

// ---------------- K2: sim BN statistics (recompute qe/ke/qk) ----------------
// grid 4096, block 256 = 4 waves; wave w handles pair P = w*4096 + bid.
__global__ __launch_bounds__(256) void k_sim(const float* __restrict__ qkv,
                                             const float* __restrict__ rel,
                                             const float* __restrict__ sqkv,
                                             const float* __restrict__ bqg,
                                             const float* __restrict__ bqb,
                                             float* __restrict__ ssim) {
    __shared__ float relS[8 * 64];
    __shared__ float qkS[4][8 * 33];
    __shared__ __attribute__((aligned(16))) float qeS[4][32 * 36];
    __shared__ __attribute__((aligned(16))) float keS[4][32 * 36];
    __shared__ float statS[4][6];
    int t = threadIdx.x;
    int wv = t >> 6, l = t & 63;
    int bid = blockIdx.x;
    int g = bid & 7;                      // same g for all 4 waves
    int n = wv * 512 + (bid >> 3);
    #pragma unroll
    for (int k = 0; k < 2; ++k) {
        int slot = t + 256 * k;
        int c = slot >> 6, d = slot & 63;
        relS[slot] = (d < 63) ? rel[c * 63 + d] : 0.0f;
    }
    {   // stage BN(qkv) q/k channels (8x32) with inline affine from stats
        int c = l >> 3, l4 = l & 7;
        int ch = g * 16 + c;
        const float* qn = qkv + (size_t)n * 4096 + g * 512;
        float4 qv = *(const float4*)(qn + c * 32 + 4 * l4);
        float mu = sqkv[ch] * (1.0f / 65536.0f);
        float var = sqkv[128 + ch] * (1.0f / 65536.0f) - mu * mu;
        float aa = bqg[ch] * rsqrtf(var + 1e-5f);
        float bb = bqb[ch] - mu * aa;
        float* dst = &qkS[wv][c * 33 + 4 * l4];
        dst[0] = aa * qv.x + bb; dst[1] = aa * qv.y + bb;
        dst[2] = aa * qv.z + bb; dst[3] = aa * qv.w + bb;
    }
    __syncthreads();
    // qe/ke: qe[i][j] = sum_c qhat[c][i] * rel[c][i-j+31]
    int j = l & 31, h = l >> 5;
    float sqe = 0, sqe2 = 0, ske = 0, ske2 = 0;
    #pragma unroll 4
    for (int ii = 0; ii < 16; ++ii) {
        int i = h + 2 * ii;
        int dd = i - j + 31;
        float qe = 0, ke = 0;
        #pragma unroll
        for (int c = 0; c < 4; ++c) {
            qe += qkS[wv][c * 33 + i] * relS[c * 64 + dd];
            ke += qkS[wv][(4 + c) * 33 + i] * relS[(4 + c) * 64 + dd];
        }
        qeS[wv][i * 36 + j] = qe;
        keS[wv][i * 36 + j] = ke;
        sqe += qe; sqe2 += qe * qe; ske += ke; ske2 += ke * ke;
    }
    __syncthreads();
    // qk[i][j] = sum_p qe[p][i]*ke[p][j], 4x4 register tile
    int ti = l >> 3, tj = l & 7;
    float acc[4][4] = {};
    #pragma unroll 8
    for (int p = 0; p < 32; ++p) {
        float4 q4 = *(const float4*)&qeS[wv][p * 36 + 4 * ti];
        float4 k4 = *(const float4*)&keS[wv][p * 36 + 4 * tj];
        float qa[4] = {q4.x, q4.y, q4.z, q4.w};
        float ka[4] = {k4.x, k4.y, k4.z, k4.w};
        #pragma unroll
        for (int a = 0; a < 4; ++a)
            #pragma unroll
            for (int bb2 = 0; bb2 < 4; ++bb2) acc[a][bb2] += qa[a] * ka[bb2];
    }
    float s1 = 0, s2 = 0;
    #pragma unroll
    for (int a = 0; a < 4; ++a)
        #pragma unroll
        for (int bb2 = 0; bb2 < 4; ++bb2) { s1 += acc[a][bb2]; s2 += acc[a][bb2] * acc[a][bb2]; }
    s1 = wave_reduce_sum(s1);   s2 = wave_reduce_sum(s2);
    sqe = wave_reduce_sum(sqe); sqe2 = wave_reduce_sum(sqe2);
    ske = wave_reduce_sum(ske); ske2 = wave_reduce_sum(ske2);
    if (l == 0) {
        statS[wv][0] = s1;  statS[wv][1] = s2;
        statS[wv][2] = sqe; statS[wv][3] = sqe2;
        statS[wv][4] = ske; statS[wv][5] = ske2;
    }
    __syncthreads();
    if (t < 6) {
        float tot = statS[0][t] + statS[1][t] + statS[2][t] + statS[3][t];
        int base = (t >> 1) * 8 + ((t & 1) ? 24 : 0);  // sums at 0/8/16, sqs at 24/32/40
        atomicAdd(&ssim[base + g], tot);
    }
}

// ---------------- K3: full attention ----------------
__global__ __launch_bounds__(256) void k_attn(const float* __restrict__ qkv,
                                              const float* __restrict__ rel,
                                              const float* __restrict__ sqkv,
                                              const float* __restrict__ bqg,
                                              const float* __restrict__ bqb,
                                              const float* __restrict__ ssim,
                                              const float* __restrict__ bsg,
                                              const float* __restrict__ bsb,
                                              float* __restrict__ oraw,
                                              float* __restrict__ sout) {
    __shared__ float relS[16 * 64];
    __shared__ float qkS[4][8 * 33];
    __shared__ float vS[4][8 * 33];
    __shared__ __attribute__((aligned(16))) float qeS[4][32 * 36];
    __shared__ __attribute__((aligned(16))) float keS[4][32 * 36];
    __shared__ float pS[4][32 * 33];
    __shared__ float statO[4][32];
    int t = threadIdx.x;
    int wv = t >> 6, l = t & 63;
    int bid = blockIdx.x;
    int g = bid & 7;
    int n = wv * 512 + (bid >> 3);
    // inline sim-BN affine (after k_sim)
    float aQK, aQE, aKE, csum;
    {
        float m0 = ssim[g] * (1.0f / 2097152.0f);
        float v0 = ssim[24 + g] * (1.0f / 2097152.0f) - m0 * m0;
        aQK = bsg[g] * rsqrtf(v0 + 1e-5f);
        float b0 = bsb[g] - m0 * aQK;
        float m1 = ssim[8 + g] * (1.0f / 2097152.0f);
        float v1 = ssim[32 + g] * (1.0f / 2097152.0f) - m1 * m1;
        aQE = bsg[8 + g] * rsqrtf(v1 + 1e-5f);
        float b1 = bsb[8 + g] - m1 * aQE;
        float m2 = ssim[16 + g] * (1.0f / 2097152.0f);
        float v2 = ssim[40 + g] * (1.0f / 2097152.0f) - m2 * m2;
        aKE = bsg[16 + g] * rsqrtf(v2 + 1e-5f);
        float b2 = bsb[16 + g] - m2 * aKE;
        csum = b0 + b1 + b2;
    }
    #pragma unroll
    for (int k = 0; k < 4; ++k) {
        int slot = t + 256 * k;
        int c = slot >> 6, d = slot & 63;
        relS[slot] = (d < 63) ? rel[c * 63 + d] : 0.0f;
    }
    {   // stage q/k (ch 0..7) and v (ch 8..15), inline qkv-BN affine
        const float* qn = qkv + (size_t)n * 4096 + g * 512;
        #pragma unroll
        for (int r = 0; r < 2; ++r) {
            int fi = l + 64 * r;
            int c = fi >> 3, l4 = fi & 7;
            int ch = g * 16 + c;
            float4 qv = *(const float4*)(qn + c * 32 + 4 * l4);
            float mu = sqkv[ch] * (1.0f / 65536.0f);
            float var = sqkv[128 + ch] * (1.0f / 65536.0f) - mu * mu;
            float aa = bqg[ch] * rsqrtf(var + 1e-5f);
            float bb = bqb[ch] - mu * aa;
            float* dst = (r == 0) ? &qkS[wv][c * 33 + 4 * l4]
                                  : &vS[wv][(c - 8) * 33 + 4 * l4];
            dst[0] = aa * qv.x + bb; dst[1] = aa * qv.y + bb;
            dst[2] = aa * qv.z + bb; dst[3] = aa * qv.w + bb;
        }
    }
    __syncthreads();
    int j = l & 31, h = l >> 5;
    #pragma unroll 4
    for (int ii = 0; ii < 16; ++ii) {
        int i = h + 2 * ii;
        int dd = i - j + 31;
        float qe = 0, ke = 0;
        #pragma unroll
        for (int c = 0; c < 4; ++c) {
            qe += qkS[wv][c * 33 + i] * relS[c * 64 + dd];
            ke += qkS[wv][(4 + c) * 33 + i] * relS[(4 + c) * 64 + dd];
        }
        qeS[wv][i * 36 + j] = qe;
        keS[wv][i * 36 + j] = ke;
    }
    __syncthreads();
    int ti = l >> 3, tj = l & 7;
    float acc[4][4] = {};
    #pragma unroll 8
    for (int p = 0; p < 32; ++p) {
        float4 q4 = *(const float4*)&qeS[wv][p * 36 + 4 * ti];
        float4 k4 = *(const float4*)&keS[wv][p * 36 + 4 * tj];
        float qa[4] = {q4.x, q4.y, q4.z, q4.w};
        float ka[4] = {k4.x, k4.y, k4.z, k4.w};
        #pragma unroll
        for (int a = 0; a < 4; ++a)
            #pragma unroll
            for (int bb2 = 0; bb2 < 4; ++bb2) acc[a][bb2] += qa[a] * ka[bb2];
    }
    // sim = aQK*qk + aQE*qe + aKE*ke + csum; row softmax; store P
    #pragma unroll
    for (int a = 0; a < 4; ++a) {
        int ia = 4 * ti + a;
        float4 qr = *(const float4*)&qeS[wv][ia * 36 + 4 * tj];
        float4 kr = *(const float4*)&keS[wv][ia * 36 + 4 * tj];
        float s0 = aQK * acc[a][0] + aQE * qr.x + aKE * kr.x + csum;
        float s1 = aQK * acc[a][1] + aQE * qr.y + aKE * kr.y + csum;
        float s2 = aQK * acc[a][2] + aQE * qr.z + aKE * kr.z + csum;
        float s3 = aQK * acc[a][3] + aQE * qr.w + aKE * kr.w + csum;
        float mx = fmaxf(fmaxf(s0, s1), fmaxf(s2, s3));
        mx = oct_reduce_max(mx);
        float e0 = __expf(s0 - mx), e1 = __expf(s1 - mx);
        float e2 = __expf(s2 - mx), e3 = __expf(s3 - mx);
        float den = oct_reduce_sum(e0 + e1 + e2 + e3);
        float inv = __fdividef(1.0f, den);
        float* pr = &pS[wv][ia * 33 + 4 * tj];
        pr[0] = e0 * inv; pr[1] = e1 * inv; pr[2] = e2 * inv; pr[3] = e3 * inv;
    }
    __syncthreads();
    // PV: am[c][i] = sum_j p[i][j] vhat[c][j]; ame[c][i] = sum_j p[i][j] rel[8+c][i-j+31]
    int i2 = l & 31, h2 = l >> 5;
    float am[4] = {}, ame[4] = {};
    #pragma unroll 4
    for (int jj = 0; jj < 32; ++jj) {
        float pv = pS[wv][i2 * 33 + jj];
        int dd = i2 - jj + 31;
        #pragma unroll
        for (int cc = 0; cc < 4; ++cc) {
            am[cc]  += pv * vS[wv][(4 * h2 + cc) * 33 + jj];
            ame[cc] += pv * relS[(8 + 4 * h2 + cc) * 64 + dd];
        }
    }
    float* on = oraw + (size_t)n * 4096 + g * 512;
    #pragma unroll
    for (int cc = 0; cc < 4; ++cc) {
        int c = 4 * h2 + cc;
        on[(2 * c) * 32 + i2] = am[cc];
        on[(2 * c + 1) * 32 + i2] = ame[cc];
    }
    #pragma unroll
    for (int cc = 0; cc < 4; ++cc) {
        float a1 = half_reduce_sum(am[cc]);
        float a2 = half_reduce_sum(am[cc] * am[cc]);
        float e1 = half_reduce_sum(ame[cc]);
        float e2 = half_reduce_sum(ame[cc] * ame[cc]);
        if (i2 == 0) {
            int c = 4 * h2 + cc;
            statO[wv][c * 4 + 0] = a1; statO[wv][c * 4 + 1] = a2;
            statO[wv][c * 4 + 2] = e1; statO[wv][c * 4 + 3] = e2;
        }
    }
    __syncthreads();
    if (t < 32) {
        int c = t >> 2, k = t & 3;
        float tot = statO[0][c * 4 + k] + statO[1][c * 4 + k]
                  + statO[2][c * 4 + k] + statO[3][c * 4 + k];
        int och = g * 16 + 2 * c + ((k >> 1) & 1);
        atomicAdd(&sout[((k & 1) ? 128 : 0) + och], tot);
    }
}

// ---------------- K4: out BN (inline affine) + pair-sum + transpose ----------------
__global__ __launch_bounds__(256) void k_out(const float* __restrict__ oraw,
                                             const float* __restrict__ sout,
                                             const float* __restrict__ bog,
                                             const float* __restrict__ bob,
                                             float* __restrict__ out) {
    int gid = blockIdx.x * 256 + threadIdx.x;
    int l4 = gid & 7;
    int rest = gid >> 3;
    int w2 = rest & 31; rest >>= 5;
    int hh = rest & 31; rest >>= 5;
    int oc = rest & 63;
    int b = rest >> 6;
    int n = b * 1024 + hh * 32 + w2;
    int c0 = 2 * oc, c1 = 2 * oc + 1;
    float mu0 = sout[c0] * (1.0f / 65536.0f);
    float v0 = sout[128 + c0] * (1.0f / 65536.0f) - mu0 * mu0;
    float a0 = bog[c0] * rsqrtf(v0 + 1e-5f);
    float b0 = bob[c0] - mu0 * a0;
    float mu1 = sout[c1] * (1.0f / 65536.0f);
    float v1 = sout[128 + c1] * (1.0f / 65536.0f) - mu1 * mu1;
    float a1 = bog[c1] * rsqrtf(v1 + 1e-5f);
    float b1 = bob[c1] - mu1 * a1;
    float cc = b0 + b1;
    const float4 r0 = *(const float4*)(oraw + (size_t)n * 4096 + oc * 64 + l4 * 4);
    const float4 r1 = *(const float4*)(oraw + (size_t)n * 4096 + oc * 64 + 32 + l4 * 4);
    float4 o;
    o.x = a0 * r0.x + a1 * r1.x + cc;
    o.y = a0 * r0.y + a1 * r1.y + cc;
    o.z = a0 * r0.z + a1 * r1.z + cc;
    o.w = a0 * r0.w + a1 * r1.w + cc;
    *((float4*)out + gid) = o;
}

extern "C" void kernel_launch(void* const* d_in, const int* in_sizes, int n_in,
                              void* d_out, int out_size, void* d_ws, size_t ws_size,
                              hipStream_t stream) {
    const float* x   = (const float*)d_in[0];
    const float* w   = (const float*)d_in[1];
    const float* bqg = (const float*)d_in[2];
    const float* bqb = (const float*)d_in[3];
    const float* bsg = (const float*)d_in[4];
    const float* bsb = (const float*)d_in[5];
    const float* bog = (const float*)d_in[6];
    const float* bob = (const float*)d_in[7];
    const float* rel = (const float*)d_in[8];

    float* ws    = (float*)d_ws;
    float* qkv   = ws;                    // 8388608 floats
    float* oraw  = ws + 8388608;          // 8388608 floats
    float* stats = ws + 16777216;         // sqkv 256 | ssim 48 | sout 256
    float* sqkv  = stats;
    float* ssim  = stats + 256;
    float* sout  = stats + 304;

    hipMemsetAsync(stats, 0, 560 * sizeof(float), stream);

    k_qkv<<<4096, 128, 0, stream>>>(x, w, qkv, sqkv);
    k_sim<<<4096, 256, 0, stream>>>(qkv, rel, sqkv, bqg, bqb, ssim);
    k_attn<<<4096, 256, 0, stream>>>(qkv, rel, sqkv, bqg, bqb, ssim, bsg, bsb, oraw, sout);
    k_out<<<4096, 256, 0, stream>>>(oraw, sout, bog, bob, (float*)d_out);
}